// Round 13
// baseline (176.894 us; speedup 1.0000x reference)
//
#include <hip/hip_runtime.h>

// N = 8,388,608 rows, C = 3 classes (fp32 log-probs), int32 labels.
// out = -sum_i( w_i * pre[i, y_i] ) / N, w_i = (|argmax(pre_i) - y_i| == 2) ? weight : 1
//
// History (kernel-only; total dur_us carries ~121-125 us of harness poison fills):
//   R0 strided+atomic ~49 | R1 coalesced+barrier 63.5 | R2 wave-private ~50
//   R3 persistent+atomic ~52 | R4 persistent LDS no-atomic ~33 (4.06 TB/s) BEST
//   R5 register-direct 48B-stride ~46 (txn inflation NOT free)
//   R6 no-drain pipelined: FAILED absmax 0.28 -> cross-iter LDS reuse WITHOUT an
//      interposed lgkmcnt(0) drain races on gfx950. The drain is load-bearing.
//
// R13 (this): keep R4's full per-iter drain (correct under any DS ordering
// model) but reorder issue so the drain stops serializing two LDS round-trips:
//   iter k: ds_read chunk k from buf[k&1] (written & drained last iter)
//           -> issue globals chunk k+2 -> ds_write chunk k+1 into buf[(k+1)&1]
//           -> lgkmcnt(0) drain -> compute chunk k.
//   One fence/iter covers RAW (this iter's writes vs next iter's reads) AND
//   WAR (this iter's reads vs next iter's writes). Read latency overlaps
//   global-issue + write-issue + drain instead of being exposed after it.
//   Worst case (compiler reorders read/write issue) == R4's 33 us. Downside 0.

typedef float v4f __attribute__((ext_vector_type(4)));

#define N_ROWS   8388608
#define BLOCK    256
#define GRID     1024
#define WPB      (BLOCK / 64)                  // 4 waves/block
#define NWAVES   (GRID * WPB)                  // 4096
#define CHUNK    256                           // rows per wave-iteration
#define NITER    (N_ROWS / (NWAVES * CHUNK))   // 8
#define ROWS_PW  (CHUNK * NITER)               // 2048 contiguous rows per wave

__global__ __launch_bounds__(BLOCK) void nll_main(
        const float* __restrict__ pre,
        const int*   __restrict__ y_true,
        const float* __restrict__ wptr,
        float*       __restrict__ partial) {
    __shared__ float tile[WPB][2][768];  // 2 LDS chunk-buffers per wave (24 KiB)
    __shared__ float red[WPB];

    const float wgt  = wptr[0];
    const int   t    = threadIdx.x;
    const int   lane = t & 63;
    const int   wv   = t >> 6;
    const int   W    = (int)blockIdx.x * WPB + wv;   // global wave id [0, 4096)

    const v4f* __restrict__ pre4 = (const v4f*)pre;
    const int fbW = W * (ROWS_PW * 3 / 4);   // float4 base (max ~6.29M, fits int)
    const int ybW = W * ROWS_PW;             // row base

    v4f v[2][3];     // pre regs: chunk k+2 loaded at iter k into v[k&1],
                     //           consumed by ds_write at iter k+1. 2 bufs exact.
    int yv[3][4];    // labels: loaded iter k (chunk k+2), consumed iter k+2.

    // ---- prologue: chunks 0,1 in flight; stage chunk 0; drain --------------
    #pragma unroll
    for (int p = 0; p < 2; ++p) {
        const int fb = fbW + p * 192;
        const int yb = ybW + p * 256;
        v[p][0] = pre4[fb +       lane];       // 16B lane stride: coalesced
        v[p][1] = pre4[fb +  64 + lane];
        v[p][2] = pre4[fb + 128 + lane];
        yv[p][0] = y_true[yb +       lane];    // 4B lane stride: coalesced
        yv[p][1] = y_true[yb +  64 + lane];
        yv[p][2] = y_true[yb + 128 + lane];
        yv[p][3] = y_true[yb + 192 + lane];
    }
    {   // stage chunk 0 (compiler waits vmcnt for chunk-0 pre only)
        v4f* s4 = (v4f*)tile[wv][0];
        s4[       lane] = v[0][0];
        s4[ 64 +  lane] = v[0][1];
        s4[128 +  lane] = v[0][2];
    }
    asm volatile("s_waitcnt lgkmcnt(0)" ::: "memory");   // chunk-0 writes done

    float acc = 0.0f;
    #pragma unroll
    for (int k = 0; k < NITER; ++k) {        // fully unrolled: all indices static
        // 1) READ chunk k from buf[k&1]. Its writes (iter k-1 / prologue) were
        //    drained by the previous fence. Issue first: read latency overlaps
        //    the global-issue + write-issue + drain below.
        const float* slice = tile[wv][k & 1];
        float p[4][3];
        #pragma unroll
        for (int m = 0; m < 4; ++m) {
            // Row r = chunkbase + lane + 64m -> LDS word 3*lane+192m: stride-3
            // across lanes, gcd(3,32)=1 -> 2 lanes/bank (free on CDNA4).
            const int w0 = 3 * lane + 192 * m;
            p[m][0] = slice[w0 + 0];
            p[m][1] = slice[w0 + 1];
            p[m][2] = slice[w0 + 2];
        }

        // 2) issue globals for chunk k+2 (keeps ~2 chunks in flight per wave).
        if (k + 2 < NITER) {
            const int fb = fbW + (k + 2) * 192;
            const int yb = ybW + (k + 2) * 256;
            v[k & 1][0] = pre4[fb +       lane];
            v[k & 1][1] = pre4[fb +  64 + lane];
            v[k & 1][2] = pre4[fb + 128 + lane];
            yv[(k + 2) % 3][0] = y_true[yb +       lane];
            yv[(k + 2) % 3][1] = y_true[yb +  64 + lane];
            yv[(k + 2) % 3][2] = y_true[yb + 128 + lane];
            yv[(k + 2) % 3][3] = y_true[yb + 192 + lane];
        }

        // 3) WRITE chunk k+1 into the other buffer (source regs loaded at
        //    iter k-1: vmcnt nearly satisfied after a full iteration in flight).
        if (k + 1 < NITER) {
            v4f* s4 = (v4f*)tile[wv][(k + 1) & 1];
            s4[       lane] = v[(k + 1) & 1][0];
            s4[ 64 +  lane] = v[(k + 1) & 1][1];
            s4[128 +  lane] = v[(k + 1) & 1][2];
        }

        // 4) ONE fence: drains this iter's reads (WAR vs next iter's writes)
        //    and this iter's writes (RAW for next iter's reads). Correct under
        //    any DS completion-ordering model -- the R6 lesson.
        asm volatile("s_waitcnt lgkmcnt(0)" ::: "memory");

        // 5) compute chunk k from registers.
        #pragma unroll
        for (int m = 0; m < 4; ++m) {
            const float p0 = p[m][0], p1 = p[m][1], p2 = p[m][2];
            const int   tt = yv[k % 3][m];
            const float picked = (tt == 0) ? p0 : ((tt == 1) ? p1 : p2);
            // first-occurrence argmax over 3 (matches jnp.argmax tie-break)
            int   prd = 0;
            float mx  = p0;
            if (p1 > mx) { mx = p1; prd = 1; }
            if (p2 > mx) { prd = 2; }
            const bool penal = (prd - tt == 2) || (tt - prd == 2);
            acc += (penal ? wgt : 1.0f) * picked;
        }
    }

    // ---- block partial: wave shuffle + tiny LDS combine, NO atomics --------
    #pragma unroll
    for (int off = 32; off > 0; off >>= 1)
        acc += __shfl_down(acc, off, 64);

    if (lane == 0) red[wv] = acc;
    __syncthreads();                       // after ALL memory work: harmless

    if (t == 0)
        partial[blockIdx.x] = red[0] + red[1] + red[2] + red[3];
}

// Second launch on the same stream (graph-legal): reduce 1024 partials.
__global__ __launch_bounds__(256) void nll_reduce(
        const float* __restrict__ partial,
        float*       __restrict__ out) {
    const float4 p = ((const float4*)partial)[threadIdx.x];   // 256*4 = 1024
    float s = p.x + p.y + p.z + p.w;
    #pragma unroll
    for (int off = 32; off > 0; off >>= 1)
        s += __shfl_down(s, off, 64);

    __shared__ float r[4];
    if ((threadIdx.x & 63) == 0) r[threadIdx.x >> 6] = s;
    __syncthreads();
    if (threadIdx.x == 0)
        out[0] = (r[0] + r[1] + r[2] + r[3]) * (-1.0f / (float)N_ROWS);
}

extern "C" void kernel_launch(void* const* d_in, const int* in_sizes, int n_in,
                              void* d_out, int out_size, void* d_ws, size_t ws_size,
                              hipStream_t stream) {
    const float* pre  = (const float*)d_in[0];
    const int*   y    = (const int*)d_in[1];
    const float* wptr = (const float*)d_in[2];
    float* ws  = (float*)d_ws;       // 4 KiB of workspace for 1024 partials
    float* out = (float*)d_out;

    nll_main<<<GRID, BLOCK, 0, stream>>>(pre, y, wptr, ws);
    nll_reduce<<<1, 256, 0, stream>>>(ws, out);
}

// Round 15
// 175.479 us; speedup vs baseline: 1.0081x; 1.0081x over previous
//
#include <hip/hip_runtime.h>

// N = 8,388,608 rows, C = 3 classes (fp32 log-probs), int32 labels.
// out = -sum_i( w_i * pre[i, y_i] ) / N, w_i = (|argmax(pre_i) - y_i| == 2) ? weight : 1
//
// History (kernel-only; total dur_us carries ~123 us of harness poison fills):
//   R0 strided+atomic ~49 | R1 coalesced+barrier 63.5 | R2 wave-private ~50
//   R3 persistent+atomic ~52 | R4 persistent LDS no-atomic ~33 (4.06 TB/s) BEST
//   R5 register-direct 48B-stride ~46 | R6 no-drain pipeline FAILED (race)
//   R13 read-early+single-fence ~50 (fence between reads and uses pins sched)
//
// R14 (this): global_load_lds DMA staging + counted vmcnt (guide T4 / common-
// mistake #1 -- the one canonical lever not yet tried). Deletes BOTH of R4's
// per-chunk serializers: the global->VGPR->ds_write round-trip AND the full
// lgkmcnt(0) drain.
//   iter k: s_waitcnt vmcnt(7)   (7 = iter k-1's {3 DMA + 4 label} ops still
//           allowed in flight; chunk k's DMA, issued at iter k-2, is complete)
//           -> 12 ds_read chunk k from buf[k%3] (compiler emits counted lgkm)
//           -> issue chunk k+2: 3 global_load_lds -> buf[(k+2)%3] + 4 labels
//           -> compute chunk k.
//   3 LDS buffers/wave: the DMA target was read a full iteration ago and those
//   reads were consumed by compute BEFORE this DMA issues (in-order front-end)
//   -> no write-vs-pending-read window (the R6 lesson, honored without drains).
// Geometry from R4: 1024 blocks x 256 thr all co-resident; 36 KiB LDS/block
// -> still 4 blocks/CU (144 KiB), 16 waves/CU.

typedef float v4f __attribute__((ext_vector_type(4)));

#define GLL(gp, lp) __builtin_amdgcn_global_load_lds(                      \
    (const __attribute__((address_space(1))) void*)(gp),                   \
    (__attribute__((address_space(3))) void*)(lp), 16, 0, 0)

#define N_ROWS   8388608
#define BLOCK    256
#define GRID     1024
#define WPB      (BLOCK / 64)                  // 4 waves/block
#define NWAVES   (GRID * WPB)                  // 4096
#define CHUNK    256                           // rows per wave-iteration
#define NITER    (N_ROWS / (NWAVES * CHUNK))   // 8
#define ROWS_PW  (CHUNK * NITER)               // 2048 contiguous rows per wave

__global__ __launch_bounds__(BLOCK) void nll_main(
        const float* __restrict__ pre,
        const int*   __restrict__ y_true,
        const float* __restrict__ wptr,
        float*       __restrict__ partial) {
    __shared__ float tile[WPB][3][768];  // 3 DMA chunk-buffers per wave (36 KiB)
    __shared__ float red[WPB];

    const float wgt  = wptr[0];
    const int   t    = threadIdx.x;
    const int   lane = t & 63;
    const int   wv   = t >> 6;
    const int   W    = (int)blockIdx.x * WPB + wv;   // global wave id [0, 4096)

    const v4f* __restrict__ pre4 = (const v4f*)pre;
    const int fbW = W * (ROWS_PW * 3 / 4);   // float4 base (max ~6.29M, fits int)
    const int ybW = W * ROWS_PW;             // row base

    int yv[3][4];    // labels: loaded at iter k for chunk k+2, consumed iter k+2

    // ---- prologue: DMA-stage chunks 0,1 + their labels (14 vmem ops) -------
    #pragma unroll
    for (int p = 0; p < 2; ++p) {
        const int fb = fbW + p * 192;
        const int yb = ybW + p * 256;
        GLL(pre4 + fb +       lane, &tile[wv][p][  0]);   // lanes -> base+16*lane
        GLL(pre4 + fb +  64 + lane, &tile[wv][p][256]);   //   = linear layout
        GLL(pre4 + fb + 128 + lane, &tile[wv][p][512]);
        yv[p][0] = y_true[yb +       lane];               // coalesced dwords
        yv[p][1] = y_true[yb +  64 + lane];
        yv[p][2] = y_true[yb + 128 + lane];
        yv[p][3] = y_true[yb + 192 + lane];
    }

    float acc = 0.0f;
    #pragma unroll
    for (int k = 0; k < NITER; ++k) {        // fully unrolled: all indices static
        // 1) counted vmcnt: allow iter k-1's 7 ops to stay in flight; chunk k's
        //    DMA (iter k-2 / prologue) is complete. Last iter: nothing younger.
        if (k < NITER - 1) asm volatile("s_waitcnt vmcnt(7)" ::: "memory");
        else               asm volatile("s_waitcnt vmcnt(0)" ::: "memory");

        // 2) ds_read chunk k. Row r = chunkbase + lane + 64m -> LDS word
        //    3*lane + 192*m: stride-3 across lanes, gcd(3,32)=1 -> 2 lanes/bank
        //    (free on CDNA4). Compiler emits its own counted lgkmcnt waits;
        //    there are NO ds_writes anywhere, so no drain is ever needed.
        const float* slice = tile[wv][k % 3];

        // 3) issue chunk k+2: DMA into buf[(k+2)%3] + labels. That buffer was
        //    read at iter k-1 and those reads were consumed by compute before
        //    this point in program order -> no write/read window.
        if (k + 2 < NITER) {
            const int fb = fbW + (k + 2) * 192;
            const int yb = ybW + (k + 2) * 256;
            GLL(pre4 + fb +       lane, &tile[wv][(k + 2) % 3][  0]);
            GLL(pre4 + fb +  64 + lane, &tile[wv][(k + 2) % 3][256]);
            GLL(pre4 + fb + 128 + lane, &tile[wv][(k + 2) % 3][512]);
            yv[(k + 2) % 3][0] = y_true[yb +       lane];
            yv[(k + 2) % 3][1] = y_true[yb +  64 + lane];
            yv[(k + 2) % 3][2] = y_true[yb + 128 + lane];
            yv[(k + 2) % 3][3] = y_true[yb + 192 + lane];
        }

        // 4) compute chunk k (reads scheduled freely against the issue above).
        #pragma unroll
        for (int m = 0; m < 4; ++m) {
            const int   w0 = 3 * lane + 192 * m;
            const float p0 = slice[w0 + 0];
            const float p1 = slice[w0 + 1];
            const float p2 = slice[w0 + 2];
            const int   tt = yv[k % 3][m];
            const float picked = (tt == 0) ? p0 : ((tt == 1) ? p1 : p2);
            // first-occurrence argmax over 3 (matches jnp.argmax tie-break)
            int   prd = 0;
            float mx  = p0;
            if (p1 > mx) { mx = p1; prd = 1; }
            if (p2 > mx) { prd = 2; }
            const bool penal = (prd - tt == 2) || (tt - prd == 2);
            acc += (penal ? wgt : 1.0f) * picked;
        }
    }

    // ---- block partial: wave shuffle + tiny LDS combine, NO atomics --------
    #pragma unroll
    for (int off = 32; off > 0; off >>= 1)
        acc += __shfl_down(acc, off, 64);

    if (lane == 0) red[wv] = acc;
    __syncthreads();                       // after ALL memory work: harmless

    if (t == 0)
        partial[blockIdx.x] = red[0] + red[1] + red[2] + red[3];
}

// Second launch on the same stream (graph-legal): reduce 1024 partials.
__global__ __launch_bounds__(256) void nll_reduce(
        const float* __restrict__ partial,
        float*       __restrict__ out) {
    const float4 p = ((const float4*)partial)[threadIdx.x];   // 256*4 = 1024
    float s = p.x + p.y + p.z + p.w;
    #pragma unroll
    for (int off = 32; off > 0; off >>= 1)
        s += __shfl_down(s, off, 64);

    __shared__ float r[4];
    if ((threadIdx.x & 63) == 0) r[threadIdx.x >> 6] = s;
    __syncthreads();
    if (threadIdx.x == 0)
        out[0] = (r[0] + r[1] + r[2] + r[3]) * (-1.0f / (float)N_ROWS);
}

extern "C" void kernel_launch(void* const* d_in, const int* in_sizes, int n_in,
                              void* d_out, int out_size, void* d_ws, size_t ws_size,
                              hipStream_t stream) {
    const float* pre  = (const float*)d_in[0];
    const int*   y    = (const int*)d_in[1];
    const float* wptr = (const float*)d_in[2];
    float* ws  = (float*)d_ws;       // 4 KiB of workspace for 1024 partials
    float* out = (float*)d_out;

    nll_main<<<GRID, BLOCK, 0, stream>>>(pre, y, wptr, ws);
    nll_reduce<<<1, 256, 0, stream>>>(ws, out);
}

// Round 16
// 159.177 us; speedup vs baseline: 1.1113x; 1.1024x over previous
//
#include <hip/hip_runtime.h>

// N = 8,388,608 rows, C = 3 classes (fp32 log-probs), int32 labels.
// out = -sum_i( w_i * pre[i, y_i] ) / N, w_i = (|argmax(pre_i) - y_i| == 2) ? weight : 1
//
// FINAL (R4 restored): best of 9 structural variants.
// History (kernel-only; total dur_us carries ~123 us of harness poison fills):
//   R0 strided+atomic ~49 | R1 coalesced+barrier 63.5 | R2 wave-private ~50
//   R3 persistent+atomic ~52 | R4 THIS: ~33 us = 4.06 TB/s  <- BEST
//   R5 register-direct 48B-stride ~46 (L1 txn inflation not free)
//   R6 no-drain pipeline FAILED (cross-iter LDS reuse races without drain)
//   R13 read-early single-fence ~50 (fence between reads and uses pins sched)
//   R14 global_load_lds DMA + counted vmcnt ~48 (1KB DMA granularity + per-iter
//       vmcnt fence pinning; gload_lds pays only at GEMM-tile granularity)
// Structure: persistent all-resident grid (1024 blocks, 4/CU, 16 waves/CU);
// coalesced loads; 3-deep register pipeline (prefetch k+2 issued BEFORE the
// vmcnt-forcing LDS write of chunk k); wave-private LDS transpose slices with
// same-wave lgkmcnt(0) drain (load-bearing -- R6 proved); atomic-free
// two-kernel reduction (the R3->R4 +18 us win: no 1024-same-address RMW tail).

typedef float v4f __attribute__((ext_vector_type(4)));

#define N_ROWS   8388608
#define BLOCK    256
#define GRID     1024
#define WPB      (BLOCK / 64)                  // 4 waves/block
#define NWAVES   (GRID * WPB)                  // 4096
#define CHUNK    256                           // rows per wave-iteration
#define NITER    (N_ROWS / (NWAVES * CHUNK))   // 8
#define ROWS_PW  (CHUNK * NITER)               // 2048 contiguous rows per wave

__global__ __launch_bounds__(BLOCK) void nll_main(
        const float* __restrict__ pre,
        const int*   __restrict__ y_true,
        const float* __restrict__ wptr,
        float*       __restrict__ partial) {
    __shared__ float tile[WPB][2][768];  // per-wave double-buffered 3 KiB slices
    __shared__ float red[WPB];

    const float wgt  = wptr[0];
    const int   t    = threadIdx.x;
    const int   lane = t & 63;
    const int   wv   = t >> 6;
    const int   W    = (int)blockIdx.x * WPB + wv;   // global wave id [0, 4096)

    const v4f* __restrict__ pre4 = (const v4f*)pre;
    const int fbW = W * (ROWS_PW * 3 / 4);   // float4 base (max ~6.29M, fits int)
    const int ybW = W * ROWS_PW;             // row base

    // 3-deep pipeline registers (36 + 12 VGPR)
    v4f v[3][3];
    int yv[3][4];

    // ---- prologue: chunks 0 and 1 in flight (14 NT loads, all coalesced) ---
    #pragma unroll
    for (int p = 0; p < 2; ++p) {
        const int fb = fbW + p * 192;
        const int yb = ybW + p * 256;
        v[p][0] = __builtin_nontemporal_load(pre4 + fb +       lane);
        v[p][1] = __builtin_nontemporal_load(pre4 + fb +  64 + lane);
        v[p][2] = __builtin_nontemporal_load(pre4 + fb + 128 + lane);
        yv[p][0] = __builtin_nontemporal_load(y_true + yb +       lane);
        yv[p][1] = __builtin_nontemporal_load(y_true + yb +  64 + lane);
        yv[p][2] = __builtin_nontemporal_load(y_true + yb + 128 + lane);
        yv[p][3] = __builtin_nontemporal_load(y_true + yb + 192 + lane);
    }

    float acc = 0.0f;
    #pragma unroll
    for (int k = 0; k < NITER; ++k) {        // fully unrolled: all indices static
        const int b  = k % 3;                // buffer being consumed
        const int nb = (k + 2) % 3;          // buffer being refilled

        // Prefetch chunk k+2 FIRST: issued before the vmcnt-forcing LDS write,
        // so chunks k+1 and k+2 (14 loads, ~7 KB/wave) stay in flight while we
        // wait for chunk k. Per CU: 16 waves x 7 KB ~ 112 KB outstanding.
        if (k + 2 < NITER) {
            const int fb = fbW + (k + 2) * 192;
            const int yb = ybW + (k + 2) * 256;
            v[nb][0] = __builtin_nontemporal_load(pre4 + fb +       lane);
            v[nb][1] = __builtin_nontemporal_load(pre4 + fb +  64 + lane);
            v[nb][2] = __builtin_nontemporal_load(pre4 + fb + 128 + lane);
            yv[nb][0] = __builtin_nontemporal_load(y_true + yb +       lane);
            yv[nb][1] = __builtin_nontemporal_load(y_true + yb +  64 + lane);
            yv[nb][2] = __builtin_nontemporal_load(y_true + yb + 128 + lane);
            yv[nb][3] = __builtin_nontemporal_load(y_true + yb + 192 + lane);
        }

        // Stage chunk k to this wave's private slice (compiler inserts the
        // partial vmcnt for chunk k only). Linear b128 writes: conflict-free.
        float* slice = tile[wv][k & 1];
        v4f*   s4    = (v4f*)slice;
        s4[       lane] = v[b][0];
        s4[ 64 +  lane] = v[b][1];
        s4[128 +  lane] = v[b][2];

        // Drain only THIS wave's DS ops; no s_barrier anywhere in the stream.
        // Load-bearing (R6): cross-iter LDS reuse without it races.
        asm volatile("s_waitcnt lgkmcnt(0)" ::: "memory");

        #pragma unroll
        for (int m = 0; m < 4; ++m) {
            // Row r = chunkbase + lane + 64m -> LDS word 3*lane+192m: stride-3
            // across lanes, gcd(3,32)=1 -> 2 lanes/bank (free on CDNA4).
            const int   w0 = 3 * lane + 192 * m;
            const float p0 = slice[w0 + 0];
            const float p1 = slice[w0 + 1];
            const float p2 = slice[w0 + 2];
            const int   tt = yv[b][m];
            const float picked = (tt == 0) ? p0 : ((tt == 1) ? p1 : p2);
            // first-occurrence argmax over 3 (matches jnp.argmax tie-break)
            int   prd = 0;
            float mx  = p0;
            if (p1 > mx) { mx = p1; prd = 1; }
            if (p2 > mx) { prd = 2; }
            const bool penal = (prd - tt == 2) || (tt - prd == 2);
            acc += (penal ? wgt : 1.0f) * picked;
        }
        // WAR (reads of slice[k&1] at iter k vs writes at iter k+2) is
        // separated by iter k+1's lgkmcnt(0): safe.
    }

    // ---- block partial: wave shuffle + tiny LDS combine, NO atomics --------
    #pragma unroll
    for (int off = 32; off > 0; off >>= 1)
        acc += __shfl_down(acc, off, 64);

    if (lane == 0) red[wv] = acc;
    __syncthreads();                       // after ALL memory work: harmless

    if (t == 0)
        partial[blockIdx.x] = red[0] + red[1] + red[2] + red[3];
}

// Second launch on the same stream (graph-legal): reduce 1024 partials.
// Plain store to out -> no reliance on poison-negligibility anymore.
__global__ __launch_bounds__(256) void nll_reduce(
        const float* __restrict__ partial,
        float*       __restrict__ out) {
    const float4 p = ((const float4*)partial)[threadIdx.x];   // 256*4 = 1024
    float s = p.x + p.y + p.z + p.w;
    #pragma unroll
    for (int off = 32; off > 0; off >>= 1)
        s += __shfl_down(s, off, 64);

    __shared__ float r[4];
    if ((threadIdx.x & 63) == 0) r[threadIdx.x >> 6] = s;
    __syncthreads();
    if (threadIdx.x == 0)
        out[0] = (r[0] + r[1] + r[2] + r[3]) * (-1.0f / (float)N_ROWS);
}

extern "C" void kernel_launch(void* const* d_in, const int* in_sizes, int n_in,
                              void* d_out, int out_size, void* d_ws, size_t ws_size,
                              hipStream_t stream) {
    const float* pre  = (const float*)d_in[0];
    const int*   y    = (const int*)d_in[1];
    const float* wptr = (const float*)d_in[2];
    float* ws  = (float*)d_ws;       // 4 KiB of workspace for 1024 partials
    float* out = (float*)d_out;

    nll_main<<<GRID, BLOCK, 0, stream>>>(pre, y, wptr, ws);
    nll_reduce<<<1, 256, 0, stream>>>(ws, out);
}